// Round 11
// baseline (232.108 us; speedup 1.0000x reference)
//
#include <hip/hip_runtime.h>

#define NROW 4096
#define DIM  1024
#define TEMP_INV 14.285714285714286f /* 1/0.07 */
#define NBINS 2048
#define HSLOTS 2304  /* 2048 bins + 4-word pad per 32: slot(b) = b + ((b>>5)<<2) */

typedef __attribute__((ext_vector_type(8))) short bf16x8;
typedef __attribute__((ext_vector_type(4))) float f32x4;

__device__ __forceinline__ unsigned f2bf_u(float f) {
  unsigned u = __float_as_uint(f);
  return (u + 0x7FFFu + ((u >> 16) & 1u)) >> 16;  // RNE bf16
}

__device__ __forceinline__ float wave_sum_f(float v) {
#pragma unroll
  for (int off = 32; off > 0; off >>= 1) v += __shfl_down(v, off);
  return v;
}

// ---------------- Kernel 1: L2 normalize rows, emit bf16 ----------------
__global__ __launch_bounds__(256) void normalize_k(const float* __restrict__ X,
                                                   unsigned short* __restrict__ FB) {
  __shared__ float warp_s[4];
  const int row = blockIdx.x;
  const int tid = threadIdx.x;
  const float4* x4 = (const float4*)(X + (size_t)row * DIM);
  float4 v = x4[tid];  // 256 threads * 4 = 1024
  float ss = v.x * v.x + v.y * v.y + v.z * v.z + v.w * v.w;
  ss = wave_sum_f(ss);
  if ((tid & 63) == 0) warp_s[tid >> 6] = ss;
  __syncthreads();
  float total = warp_s[0] + warp_s[1] + warp_s[2] + warp_s[3];
  float inv = 1.0f / fmaxf(sqrtf(total), 1e-12f);
  ushort4 o;
  o.x = (unsigned short)f2bf_u(v.x * inv);
  o.y = (unsigned short)f2bf_u(v.y * inv);
  o.z = (unsigned short)f2bf_u(v.z * inv);
  o.w = (unsigned short)f2bf_u(v.w * inv);
  ((ushort4*)(FB + (size_t)row * DIM))[tid] = o;
}

// ---------------- Kernel 2: sim = (FB @ FB^T) * (1/T), f32 out ----------------
// REVERTED to the round-6 measured version (52.5 us, MfmaUtil 25.6, conflicts 0).
// 128x128 tile, BK=64, 4 waves, single-buffer 2-barrier K-loop, T2 swizzle
// (linear LDS dest, inverse-swizzled global source, swizzled ds_read), T1 XCD
// swizzle. Round-8 (2-phase dbuf) was neutral; round-10 (3-buf counted vmcnt,
// BK=32) was neutral-to-regressive. This is the best measured structure.
__global__ __launch_bounds__(256) void gemm_sim(const unsigned short* __restrict__ FB,
                                                float* __restrict__ C) {
  __shared__ unsigned short As[128 * 64] __attribute__((aligned(16)));  // 16 KB
  __shared__ unsigned short Bs[128 * 64] __attribute__((aligned(16)));  // 16 KB
  const int tid  = threadIdx.x;
  const int wave = tid >> 6;
  const int lane = tid & 63;
  const int wr = wave >> 1;  // wave row 0..1
  const int wc = wave & 1;   // wave col 0..1

  const int bid = blockIdx.x;
  const int swz = (bid & 7) * 128 + (bid >> 3);
  const int brow = (swz >> 5) * 128;
  const int bcol = (swz & 31) * 128;

  f32x4 acc[4][4];
#pragma unroll
  for (int m = 0; m < 4; ++m)
#pragma unroll
    for (int n = 0; n < 4; ++n) acc[m][n] = (f32x4){0.f, 0.f, 0.f, 0.f};

  const int s_rl = wave * 8 + (lane >> 3);               // + i*32
  const int s_cs = (((lane & 7) ^ (lane >> 3)) << 3);    // shorts
  const int fr  = lane & 15;
  const int fk2 = (lane >> 4) << 4;       // byte offset of k-fragment: 0/16/32/48
  const int frx = (fr & 7) << 4;

  for (int k0 = 0; k0 < DIM; k0 += 64) {
#pragma unroll
    for (int i = 0; i < 4; ++i) {
      const int rl = i * 32 + s_rl;
      const unsigned short* gA = FB + (size_t)(brow + rl) * DIM + (k0 + s_cs);
      const unsigned short* gB = FB + (size_t)(bcol + rl) * DIM + (k0 + s_cs);
      unsigned short* lA = As + (i * 32 + wave * 8) * 64;  // wave-uniform base
      unsigned short* lB = Bs + (i * 32 + wave * 8) * 64;
      __builtin_amdgcn_global_load_lds((const __attribute__((address_space(1))) unsigned int*)gA,
                                       (__attribute__((address_space(3))) unsigned int*)lA, 16, 0, 0);
      __builtin_amdgcn_global_load_lds((const __attribute__((address_space(1))) unsigned int*)gB,
                                       (__attribute__((address_space(3))) unsigned int*)lB, 16, 0, 0);
    }
    __syncthreads();  // drains vmcnt -> staged data visible

#pragma unroll
    for (int h = 0; h < 2; ++h) {       // two K=32 halves of BK=64
      const int cb = ((fk2 + h * 64) ^ frx) >> 1;  // swizzled col (shorts)
      bf16x8 af[4], bg[4];
#pragma unroll
      for (int m = 0; m < 4; ++m)
        af[m] = *(const bf16x8*)&As[(wr * 64 + m * 16 + fr) * 64 + cb];
#pragma unroll
      for (int n = 0; n < 4; ++n)
        bg[n] = *(const bf16x8*)&Bs[(wc * 64 + n * 16 + fr) * 64 + cb];
#pragma unroll
      for (int m = 0; m < 4; ++m)
#pragma unroll
        for (int n = 0; n < 4; ++n)
          acc[m][n] = __builtin_amdgcn_mfma_f32_16x16x32_bf16(af[m], bg[n], acc[m][n], 0, 0, 0);
    }
    __syncthreads();  // all reads done before next stage overwrites
  }

  const int rsub = (lane >> 4) * 4;
#pragma unroll
  for (int m = 0; m < 4; ++m)
#pragma unroll
    for (int n = 0; n < 4; ++n) {
      const int r0 = brow + wr * 64 + m * 16 + rsub;
      const int c  = bcol + wc * 64 + n * 16 + fr;
#pragma unroll
      for (int i = 0; i < 4; ++i)
        C[(size_t)(r0 + i) * NROW + c] = acc[m][n][i] * TEMP_INV;
    }
}

// ---------------- Kernel 3: per-row hard mining + loss, SINGLE PASS ----------
// One WAVE per row, 2 rows per 128-thread block, ZERO barriers (all LDS state
// is per-wave; wave-internal lgkmcnt fences only). The single streaming pass
// accumulates BOTH per-bin counts AND per-bin exp-sums (plus the threshold-
// independent possum/pc/selfv). The suffix scan that locates the k-th-largest
// bin simultaneously suffix-sums the exp bins, so negexp = sum_{b>=Bsel} esum[b]
// -- the exact same element set as the old two-pass version (same bin
// predicate), just a different fp summation order. Halves S traffic.
__global__ __launch_bounds__(128) void row_loss_k(const float* __restrict__ S,
                                                  const int* __restrict__ labels,
                                                  float* __restrict__ out) {
  __shared__ unsigned cnt[2][HSLOTS] __attribute__((aligned(16)));  // 18.4 KB
  __shared__ float   esum[2][HSLOTS] __attribute__((aligned(16)));  // 18.4 KB
  const int wave = threadIdx.x >> 6;
  const int lane = threadIdx.x & 63;
  const int row  = blockIdx.x * 2 + wave;
  const int my   = labels[row];
  unsigned* Hc = cnt[wave];
  float*    He = esum[wave];

  // zero this wave's arrays: 576 uint4 + 576 float4 over 64 lanes = 9 + 9
#pragma unroll
  for (int z = 0; z < 9; ++z) {
    ((uint4*)Hc)[z * 64 + lane]   = (uint4){0u, 0u, 0u, 0u};
    ((float4*)He)[z * 64 + lane]  = (float4){0.f, 0.f, 0.f, 0.f};
  }
  asm volatile("s_waitcnt lgkmcnt(0)" ::: "memory");  // zeros visible wave-wide

  const float4* rp = (const float4*)(S + (size_t)row * NROW);
  const int4*   lp = (const int4*)labels;

  // single fused pass: element (e,c) is column j = e*256 + lane*4 + c
  float possum = 0.f, selfv = 0.f;
  int pc = 0;
#pragma unroll 4
  for (int e = 0; e < 16; ++e) {
    float4 v4 = rp[e * 64 + lane];
    int4   lb = lp[e * 64 + lane];
    const int j0 = e * 256 + lane * 4;
#pragma unroll
    for (int c = 0; c < 4; ++c) {
      float v = ((const float*)&v4)[c];
      int l = ((const int*)&lb)[c];
      if (l != my) {
        // negative: bin provably in [101, 1946] (|sim| <= 14.42) -> no clamp
        int b = (int)((v + 16.0f) * 64.0f);
        int s = b + ((b >> 5) << 2);
        atomicAdd(&Hc[s], 1u);
        atomicAdd(&He[s], __expf(v));
      } else if (j0 + c != row) {
        possum += v; pc++;
      } else {
        selfv = v;
      }
    }
  }
  asm volatile("s_waitcnt lgkmcnt(0)" ::: "memory");  // fills visible wave-wide

  // per-lane totals over its 32 bins (slots lane*36 + 0..31)
  int   tsC = 0;
  float tsE = 0.f;
#pragma unroll
  for (int z = 0; z < 8; ++z) {
    uint4  h = *(const uint4*)&Hc[lane * 36 + z * 4];
    float4 g = *(const float4*)&He[lane * 36 + z * 4];
    tsC += (int)(h.x + h.y + h.z + h.w);
    tsE += g.x + g.y + g.z + g.w;
  }
  // suffix scan across lanes (both count and exp-sum)
  int sfxC = tsC;  float sfxE = tsE;
#pragma unroll
  for (int off = 1; off < 64; off <<= 1) {
    int   tc = __shfl_down(sfxC, off);
    float te = __shfl_down(sfxE, off);
    bool ok = (lane + off < 64);
    sfxC += ok ? tc : 0;
    sfxE += ok ? te : 0.f;
  }
  const int nneg = __shfl(sfxC, 0);  // total negatives
  int k = nneg >> 1;                 // floor(count*0.5)
  if (k < 1) k = 1;

  int   snextC = __shfl_down(sfxC, 1);
  float snextE = __shfl_down(sfxE, 1);
  if (lane == 63) { snextC = 0; snextE = 0.f; }
  const bool iscross = (sfxC >= k) && (snextC < k);

  // in-lane descent from top bin; accumulate exp alongside count
  int B = -1;
  int run = snextC;
  float eacc = snextE;
#pragma unroll
  for (int z = 7; z >= 0; --z) {
    uint4  h = *(const uint4*)&Hc[lane * 36 + z * 4];
    float4 g = *(const float4*)&He[lane * 36 + z * 4];
    if (B < 0) { run += (int)h.w; eacc += g.w; if (run >= k) B = z * 4 + 3; }
    if (B < 0) { run += (int)h.z; eacc += g.z; if (run >= k) B = z * 4 + 2; }
    if (B < 0) { run += (int)h.y; eacc += g.y; if (run >= k) B = z * 4 + 1; }
    if (B < 0) { run += (int)h.x; eacc += g.x; if (run >= k) B = z * 4 + 0; }
  }
  B = iscross ? (lane * 32 + B) : -1;

  unsigned long long mB = __ballot(B >= 0);
  float negexp = 0.f;
  if (mB != 0ull) {                  // mB == 0 only if no negatives
    int src = __ffsll(mB) - 1;
    negexp = __shfl(eacc, src);      // = sum_{b >= Bsel} esum[b]
  }

  // wave reduction of the threshold-independent accumulators
#pragma unroll
  for (int off = 32; off > 0; off >>= 1) {
    possum += __shfl_xor(possum, off);
    selfv  += __shfl_xor(selfv, off);
    pc     += __shfl_xor(pc, off);
  }
  if (lane == 0) {
    float denom = negexp + expf(selfv) + 1e-10f;
    float logd = logf(denom);
    float pcf = (float)pc;
    float mlpp = (possum - pcf * logd) / (pcf + 1e-10f);
    atomicAdd(out, -mlpp * (1.0f / (float)NROW));
  }
}

// ---------------- launcher ----------------
extern "C" void kernel_launch(void* const* d_in, const int* in_sizes, int n_in,
                              void* d_out, int out_size, void* d_ws, size_t ws_size,
                              hipStream_t stream) {
  const float* X    = (const float*)d_in[0];
  const int* labels = (const int*)d_in[1];
  float* out        = (float*)d_out;

  unsigned short* FB = (unsigned short*)d_ws;                       // 8 MB bf16
  float* S = (float*)((char*)d_ws + (size_t)NROW * DIM * 2);        // 64 MB f32

  hipMemsetAsync(out, 0, sizeof(float), stream);
  normalize_k<<<NROW, 256, 0, stream>>>(X, FB);
  gemm_sim<<<1024, 256, 0, stream>>>(FB, S);
  row_loss_k<<<NROW / 2, 128, 0, stream>>>(S, labels, out);
}

// Round 13
// 185.295 us; speedup vs baseline: 1.2526x; 1.2526x over previous
//
#include <hip/hip_runtime.h>

#define NROW 4096
#define DIM  1024
#define TEMP_INV 14.285714285714286f /* 1/0.07 */

typedef __attribute__((ext_vector_type(8))) short bf16x8;
typedef __attribute__((ext_vector_type(4))) float f32x4;

__device__ __forceinline__ unsigned f2bf_u(float f) {
  unsigned u = __float_as_uint(f);
  return (u + 0x7FFFu + ((u >> 16) & 1u)) >> 16;  // RNE bf16
}

__device__ __forceinline__ float wave_sum_f(float v) {
#pragma unroll
  for (int off = 32; off > 0; off >>= 1) v += __shfl_down(v, off);
  return v;
}

// ---------------- Kernel 1: L2 normalize rows, emit bf16 ----------------
__global__ __launch_bounds__(256) void normalize_k(const float* __restrict__ X,
                                                   unsigned short* __restrict__ FB) {
  __shared__ float warp_s[4];
  const int row = blockIdx.x;
  const int tid = threadIdx.x;
  const float4* x4 = (const float4*)(X + (size_t)row * DIM);
  float4 v = x4[tid];  // 256 threads * 4 = 1024
  float ss = v.x * v.x + v.y * v.y + v.z * v.z + v.w * v.w;
  ss = wave_sum_f(ss);
  if ((tid & 63) == 0) warp_s[tid >> 6] = ss;
  __syncthreads();
  float total = warp_s[0] + warp_s[1] + warp_s[2] + warp_s[3];
  float inv = 1.0f / fmaxf(sqrtf(total), 1e-12f);
  ushort4 o;
  o.x = (unsigned short)f2bf_u(v.x * inv);
  o.y = (unsigned short)f2bf_u(v.y * inv);
  o.z = (unsigned short)f2bf_u(v.z * inv);
  o.w = (unsigned short)f2bf_u(v.w * inv);
  ((ushort4*)(FB + (size_t)row * DIM))[tid] = o;
}

// ---------------- Kernel 2: sim = (FB @ FB^T) * (1/T), f32 out ----------------
// Round-6 measured-best structure (52.5 us, MfmaUtil 25.6, conflicts 0):
// 128x128 tile, BK=64, 4 waves, single-buffer 2-barrier K-loop, T2 swizzle
// (linear LDS dest, inverse-swizzled global source, swizzled ds_read), T1 XCD
// swizzle. Pipeline experiments (r8 2-phase dbuf: neutral; r10 3-buf counted
// vmcnt BK=32: regressive) both failed -> keep this until a measured win.
__global__ __launch_bounds__(256) void gemm_sim(const unsigned short* __restrict__ FB,
                                                float* __restrict__ C) {
  __shared__ unsigned short As[128 * 64] __attribute__((aligned(16)));  // 16 KB
  __shared__ unsigned short Bs[128 * 64] __attribute__((aligned(16)));  // 16 KB
  const int tid  = threadIdx.x;
  const int wave = tid >> 6;
  const int lane = tid & 63;
  const int wr = wave >> 1;  // wave row 0..1
  const int wc = wave & 1;   // wave col 0..1

  const int bid = blockIdx.x;
  const int swz = (bid & 7) * 128 + (bid >> 3);
  const int brow = (swz >> 5) * 128;
  const int bcol = (swz & 31) * 128;

  f32x4 acc[4][4];
#pragma unroll
  for (int m = 0; m < 4; ++m)
#pragma unroll
    for (int n = 0; n < 4; ++n) acc[m][n] = (f32x4){0.f, 0.f, 0.f, 0.f};

  const int s_rl = wave * 8 + (lane >> 3);               // + i*32
  const int s_cs = (((lane & 7) ^ (lane >> 3)) << 3);    // shorts
  const int fr  = lane & 15;
  const int fk2 = (lane >> 4) << 4;       // byte offset of k-fragment: 0/16/32/48
  const int frx = (fr & 7) << 4;

  for (int k0 = 0; k0 < DIM; k0 += 64) {
#pragma unroll
    for (int i = 0; i < 4; ++i) {
      const int rl = i * 32 + s_rl;
      const unsigned short* gA = FB + (size_t)(brow + rl) * DIM + (k0 + s_cs);
      const unsigned short* gB = FB + (size_t)(bcol + rl) * DIM + (k0 + s_cs);
      unsigned short* lA = As + (i * 32 + wave * 8) * 64;  // wave-uniform base
      unsigned short* lB = Bs + (i * 32 + wave * 8) * 64;
      __builtin_amdgcn_global_load_lds((const __attribute__((address_space(1))) unsigned int*)gA,
                                       (__attribute__((address_space(3))) unsigned int*)lA, 16, 0, 0);
      __builtin_amdgcn_global_load_lds((const __attribute__((address_space(1))) unsigned int*)gB,
                                       (__attribute__((address_space(3))) unsigned int*)lB, 16, 0, 0);
    }
    __syncthreads();  // drains vmcnt -> staged data visible

#pragma unroll
    for (int h = 0; h < 2; ++h) {       // two K=32 halves of BK=64
      const int cb = ((fk2 + h * 64) ^ frx) >> 1;  // swizzled col (shorts)
      bf16x8 af[4], bg[4];
#pragma unroll
      for (int m = 0; m < 4; ++m)
        af[m] = *(const bf16x8*)&As[(wr * 64 + m * 16 + fr) * 64 + cb];
#pragma unroll
      for (int n = 0; n < 4; ++n)
        bg[n] = *(const bf16x8*)&Bs[(wc * 64 + n * 16 + fr) * 64 + cb];
#pragma unroll
      for (int m = 0; m < 4; ++m)
#pragma unroll
        for (int n = 0; n < 4; ++n)
          acc[m][n] = __builtin_amdgcn_mfma_f32_16x16x32_bf16(af[m], bg[n], acc[m][n], 0, 0, 0);
    }
    __syncthreads();  // all reads done before next stage overwrites
  }

  const int rsub = (lane >> 4) * 4;
#pragma unroll
  for (int m = 0; m < 4; ++m)
#pragma unroll
    for (int n = 0; n < 4; ++n) {
      const int r0 = brow + wr * 64 + m * 16 + rsub;
      const int c  = bcol + wc * 64 + n * 16 + fr;
#pragma unroll
      for (int i = 0; i < 4; ++i)
        C[(size_t)(r0 + i) * NROW + c] = acc[m][n][i] * TEMP_INV;
    }
}

// ---------------- Kernel 3: hard mining + loss via REGISTER BISECTION --------
// One WAVE per row, 4 rows per 256-thread block. ZERO LDS, ZERO atomics (except
// the one global out-add), ZERO barriers. The LDS-atomic histogram was the
// bottleneck (r11: 2 atomics/elem -> 123 us, VALUBusy 6.6%).
// Pass 1: load row (64 f32/lane, kept in VGPRs with static indexing), build
//   threshold-independent accumulators (possum/pc/selfv), substitute
//   non-negatives with -1e30 in d[].
// Bisection (14 iters on [-15,15] -> width 0.0018): count(v >= mid) via 64
//   static compares + 6-shfl reduce; wave-uniform branch. Selection v >= lo
//   where count >= k; expected extras vs exact k-th threshold ~1 element
//   (~252 elems/unit density x 0.0018) -> Delta(loss) ~1e-6, far under the
//   bin-histogram version's already-passing error.
// Final: negexp = sum exp(d >= lo) in registers, wave-reduce, one atomicAdd.
__global__ __launch_bounds__(256) void row_loss_k(const float* __restrict__ S,
                                                  const int* __restrict__ labels,
                                                  float* __restrict__ out) {
  const int wave = threadIdx.x >> 6;
  const int lane = threadIdx.x & 63;
  const int row  = blockIdx.x * 4 + wave;
  const int my   = labels[row];

  const float4* rp = (const float4*)(S + (size_t)row * NROW);
  const int4*   lp = (const int4*)labels;

  float d[64];                     // this lane's 64 row elements (static idx)
  float possum = 0.f, selfv = 0.f;
  int pc = 0, nl = 0;
#pragma unroll
  for (int e = 0; e < 16; ++e) {
    float4 v4 = rp[e * 64 + lane];
    int4   lb = lp[e * 64 + lane];
    const int j0 = e * 256 + lane * 4;
#pragma unroll
    for (int c = 0; c < 4; ++c) {
      float v = ((const float*)&v4)[c];
      int   l = ((const int*)&lb)[c];
      if (l != my) {
        d[e * 4 + c] = v;          // negative: keep value
        nl++;
      } else {
        d[e * 4 + c] = -1e30f;     // sentinel: never selected (lo >= -15)
        if (j0 + c == row) selfv = v;
        else { possum += v; pc++; }
      }
    }
  }

  int nneg = nl;
#pragma unroll
  for (int off = 32; off > 0; off >>= 1) nneg += __shfl_xor(nneg, off);
  int k = nneg >> 1;               // floor(count*0.5)
  if (k < 1) k = 1;

  // bisection: invariant count(>=lo) >= k (lo=-15: all negs; nneg>=k unless
  // nneg==0, then selection stays empty as d is all sentinels)
  float lo = -15.f, hi = 15.f;
  for (int it = 0; it < 14; ++it) {
    float mid = 0.5f * (lo + hi);
    int cnt = 0;
#pragma unroll
    for (int i = 0; i < 64; ++i) cnt += (d[i] >= mid) ? 1 : 0;
#pragma unroll
    for (int off = 32; off > 0; off >>= 1) cnt += __shfl_xor(cnt, off);
    if (cnt >= k) lo = mid; else hi = mid;   // wave-uniform
  }

  float negexp = 0.f;
#pragma unroll
  for (int i = 0; i < 64; ++i) negexp += (d[i] >= lo) ? __expf(d[i]) : 0.f;

#pragma unroll
  for (int off = 32; off > 0; off >>= 1) {
    negexp += __shfl_xor(negexp, off);
    possum += __shfl_xor(possum, off);
    selfv  += __shfl_xor(selfv, off);
    pc     += __shfl_xor(pc, off);
  }
  if (lane == 0) {
    float denom = negexp + expf(selfv) + 1e-10f;
    float logd = logf(denom);
    float pcf = (float)pc;
    float mlpp = (possum - pcf * logd) / (pcf + 1e-10f);
    atomicAdd(out, -mlpp * (1.0f / (float)NROW));
  }
}

// ---------------- launcher ----------------
extern "C" void kernel_launch(void* const* d_in, const int* in_sizes, int n_in,
                              void* d_out, int out_size, void* d_ws, size_t ws_size,
                              hipStream_t stream) {
  const float* X    = (const float*)d_in[0];
  const int* labels = (const int*)d_in[1];
  float* out        = (float*)d_out;

  unsigned short* FB = (unsigned short*)d_ws;                       // 8 MB bf16
  float* S = (float*)((char*)d_ws + (size_t)NROW * DIM * 2);        // 64 MB f32

  hipMemsetAsync(out, 0, sizeof(float), stream);
  normalize_k<<<NROW, 256, 0, stream>>>(X, FB);
  gemm_sim<<<1024, 256, 0, stream>>>(FB, S);
  row_loss_k<<<NROW / 4, 256, 0, stream>>>(S, labels, out);
}

// Round 14
// 185.291 us; speedup vs baseline: 1.2527x; 1.0000x over previous
//
#include <hip/hip_runtime.h>

#define NROW 4096
#define DIM  1024
#define TEMP_INV 14.285714285714286f /* 1/0.07 */

typedef __attribute__((ext_vector_type(8))) short bf16x8;
typedef __attribute__((ext_vector_type(4))) float f32x4;

__device__ __forceinline__ unsigned f2bf_u(float f) {
  unsigned u = __float_as_uint(f);
  return (u + 0x7FFFu + ((u >> 16) & 1u)) >> 16;  // RNE bf16
}

__device__ __forceinline__ float wave_sum_f(float v) {
#pragma unroll
  for (int off = 32; off > 0; off >>= 1) v += __shfl_down(v, off);
  return v;
}

// ---------------- Kernel 1: L2 normalize rows, emit bf16 ----------------
__global__ __launch_bounds__(256) void normalize_k(const float* __restrict__ X,
                                                   unsigned short* __restrict__ FB) {
  __shared__ float warp_s[4];
  const int row = blockIdx.x;
  const int tid = threadIdx.x;
  const float4* x4 = (const float4*)(X + (size_t)row * DIM);
  float4 v = x4[tid];  // 256 threads * 4 = 1024
  float ss = v.x * v.x + v.y * v.y + v.z * v.z + v.w * v.w;
  ss = wave_sum_f(ss);
  if ((tid & 63) == 0) warp_s[tid >> 6] = ss;
  __syncthreads();
  float total = warp_s[0] + warp_s[1] + warp_s[2] + warp_s[3];
  float inv = 1.0f / fmaxf(sqrtf(total), 1e-12f);
  ushort4 o;
  o.x = (unsigned short)f2bf_u(v.x * inv);
  o.y = (unsigned short)f2bf_u(v.y * inv);
  o.z = (unsigned short)f2bf_u(v.z * inv);
  o.w = (unsigned short)f2bf_u(v.w * inv);
  ((ushort4*)(FB + (size_t)row * DIM))[tid] = o;
}

// ---------------- Kernel 2: sim = (FB @ FB^T) * (1/T), f32 out ----------------
// Round-6 K-loop (measured best; MfmaUtil 25.6, conflicts 0) + NEW epilogue.
// Round-6 profile showed FETCH_SIZE ~= 64MB = sizeof(C): the old 4B-scalar
// epilogue covered only 64B per wave-instruction -> partial-line stores ->
// TCC write-allocate fetched ALL of C from HBM before overwriting (RMW).
// New epilogue: per-wave 4KB LDS repack (As is dead after the K-loop; regions
// disjoint per wave -> ZERO barriers, wave-internal lgkmcnt fences only), then
// float4 stores: 64 lanes x 16B = 1KB contiguous = 8 full 128B lines/instr.
// LDS bank swizzle col ^= ((row>>2)&3)<<4 keeps write 2-way / read even (free).
__global__ __launch_bounds__(256) void gemm_sim(const unsigned short* __restrict__ FB,
                                                float* __restrict__ C) {
  __shared__ unsigned short As[128 * 64] __attribute__((aligned(16)));  // 16 KB
  __shared__ unsigned short Bs[128 * 64] __attribute__((aligned(16)));  // 16 KB
  const int tid  = threadIdx.x;
  const int wave = tid >> 6;
  const int lane = tid & 63;
  const int wr = wave >> 1;  // wave row 0..1
  const int wc = wave & 1;   // wave col 0..1

  const int bid = blockIdx.x;
  const int swz = (bid & 7) * 128 + (bid >> 3);
  const int brow = (swz >> 5) * 128;
  const int bcol = (swz & 31) * 128;

  f32x4 acc[4][4];
#pragma unroll
  for (int m = 0; m < 4; ++m)
#pragma unroll
    for (int n = 0; n < 4; ++n) acc[m][n] = (f32x4){0.f, 0.f, 0.f, 0.f};

  const int s_rl = wave * 8 + (lane >> 3);               // + i*32
  const int s_cs = (((lane & 7) ^ (lane >> 3)) << 3);    // shorts
  const int fr  = lane & 15;
  const int fk2 = (lane >> 4) << 4;       // byte offset of k-fragment: 0/16/32/48
  const int frx = (fr & 7) << 4;

  for (int k0 = 0; k0 < DIM; k0 += 64) {
#pragma unroll
    for (int i = 0; i < 4; ++i) {
      const int rl = i * 32 + s_rl;
      const unsigned short* gA = FB + (size_t)(brow + rl) * DIM + (k0 + s_cs);
      const unsigned short* gB = FB + (size_t)(bcol + rl) * DIM + (k0 + s_cs);
      unsigned short* lA = As + (i * 32 + wave * 8) * 64;  // wave-uniform base
      unsigned short* lB = Bs + (i * 32 + wave * 8) * 64;
      __builtin_amdgcn_global_load_lds((const __attribute__((address_space(1))) unsigned int*)gA,
                                       (__attribute__((address_space(3))) unsigned int*)lA, 16, 0, 0);
      __builtin_amdgcn_global_load_lds((const __attribute__((address_space(1))) unsigned int*)gB,
                                       (__attribute__((address_space(3))) unsigned int*)lB, 16, 0, 0);
    }
    __syncthreads();  // drains vmcnt -> staged data visible

#pragma unroll
    for (int h = 0; h < 2; ++h) {       // two K=32 halves of BK=64
      const int cb = ((fk2 + h * 64) ^ frx) >> 1;  // swizzled col (shorts)
      bf16x8 af[4], bg[4];
#pragma unroll
      for (int m = 0; m < 4; ++m)
        af[m] = *(const bf16x8*)&As[(wr * 64 + m * 16 + fr) * 64 + cb];
#pragma unroll
      for (int n = 0; n < 4; ++n)
        bg[n] = *(const bf16x8*)&Bs[(wc * 64 + n * 16 + fr) * 64 + cb];
#pragma unroll
      for (int m = 0; m < 4; ++m)
#pragma unroll
        for (int n = 0; n < 4; ++n)
          acc[m][n] = __builtin_amdgcn_mfma_f32_16x16x32_bf16(af[m], bg[n], acc[m][n], 0, 0, 0);
    }
    __syncthreads();  // all reads done before next stage overwrites
  }
  // last loop iteration's trailing __syncthreads: all waves done with As/Bs.

  // ---- epilogue: per-wave LDS repack -> full-line float4 stores ----
  float* fw = (float*)As + wave * 1024;   // 4KB per wave, disjoint
  const int rsub   = (lane >> 4) * 4;
  const int g      = lane >> 4;           // == (row>>2)&3 for written rows
  const int col_rd = (lane & 15) * 4;
#pragma unroll
  for (int m = 0; m < 4; ++m) {
#pragma unroll
    for (int n = 0; n < 4; ++n) {
      const int colw = (n * 16 + fr) ^ (g << 4);   // bank swizzle
#pragma unroll
      for (int i = 0; i < 4; ++i)
        fw[(rsub + i) * 64 + colw] = acc[m][n][i] * TEMP_INV;
    }
    asm volatile("s_waitcnt lgkmcnt(0)" ::: "memory");  // writes visible (wave-local)
#pragma unroll
    for (int j = 0; j < 4; ++j) {
      // row j*4+g has swizzle key (row>>2)&3 == j; unswizzled data col = col_rd
      float4 v = *(const float4*)&fw[(j * 4 + g) * 64 + (col_rd ^ (j << 4))];
      const int r = brow + wr * 64 + m * 16 + j * 4 + g;
      const int c = bcol + wc * 64 + col_rd;
      *(float4*)&C[(size_t)r * NROW + c] = v;
    }
    asm volatile("s_waitcnt lgkmcnt(0)" ::: "memory");  // reads done before next m overwrites
  }
}

// ---------------- Kernel 3: hard mining + loss via REGISTER BISECTION --------
// One WAVE per row, 4 rows per 256-thread block. Zero LDS/atomics/barriers.
// r13 post-mortem: VGPR_Count=44 proved d[64] was SPILLED to scratch (needs
// >=64 VGPR if resident) -> 74 us. Fix: __launch_bounds__(256, 1) = min 1
// wave/EU -> VGPR budget up to 512 (m08: no spill through 450) -> d[] stays
// in registers. Occupancy drops to ~4-8 waves/CU but the spill round-trips go.
__global__ __launch_bounds__(256, 1) void row_loss_k(const float* __restrict__ S,
                                                     const int* __restrict__ labels,
                                                     float* __restrict__ out) {
  const int wave = threadIdx.x >> 6;
  const int lane = threadIdx.x & 63;
  const int row  = blockIdx.x * 4 + wave;
  const int my   = labels[row];

  const float4* rp = (const float4*)(S + (size_t)row * NROW);
  const int4*   lp = (const int4*)labels;

  float d[64];                     // this lane's 64 row elements (static idx)
  float possum = 0.f, selfv = 0.f;
  int pc = 0, nl = 0;
#pragma unroll
  for (int e = 0; e < 16; ++e) {
    float4 v4 = rp[e * 64 + lane];
    int4   lb = lp[e * 64 + lane];
    const int j0 = e * 256 + lane * 4;
#pragma unroll
    for (int c = 0; c < 4; ++c) {
      float v = ((const float*)&v4)[c];
      int   l = ((const int*)&lb)[c];
      if (l != my) {
        d[e * 4 + c] = v;          // negative: keep value
        nl++;
      } else {
        d[e * 4 + c] = -1e30f;     // sentinel: never selected (lo >= -15)
        if (j0 + c == row) selfv = v;
        else { possum += v; pc++; }
      }
    }
  }

  int nneg = nl;
#pragma unroll
  for (int off = 32; off > 0; off >>= 1) nneg += __shfl_xor(nneg, off);
  int k = nneg >> 1;               // floor(count*0.5)
  if (k < 1) k = 1;

  // bisection: invariant count(>=lo) >= k (lo=-15: all negs; nneg>=k unless
  // nneg==0, then selection stays empty as d is all sentinels)
  float lo = -15.f, hi = 15.f;
  for (int it = 0; it < 14; ++it) {
    float mid = 0.5f * (lo + hi);
    int cnt = 0;
#pragma unroll
    for (int i = 0; i < 64; ++i) cnt += (d[i] >= mid) ? 1 : 0;
#pragma unroll
    for (int off = 32; off > 0; off >>= 1) cnt += __shfl_xor(cnt, off);
    if (cnt >= k) lo = mid; else hi = mid;   // wave-uniform
  }

  float negexp = 0.f;
#pragma unroll
  for (int i = 0; i < 64; ++i) negexp += (d[i] >= lo) ? __expf(d[i]) : 0.f;

#pragma unroll
  for (int off = 32; off > 0; off >>= 1) {
    negexp += __shfl_xor(negexp, off);
    possum += __shfl_xor(possum, off);
    selfv  += __shfl_xor(selfv, off);
    pc     += __shfl_xor(pc, off);
  }
  if (lane == 0) {
    float denom = negexp + expf(selfv) + 1e-10f;
    float logd = logf(denom);
    float pcf = (float)pc;
    float mlpp = (possum - pcf * logd) / (pcf + 1e-10f);
    atomicAdd(out, -mlpp * (1.0f / (float)NROW));
  }
}

// ---------------- launcher ----------------
extern "C" void kernel_launch(void* const* d_in, const int* in_sizes, int n_in,
                              void* d_out, int out_size, void* d_ws, size_t ws_size,
                              hipStream_t stream) {
  const float* X    = (const float*)d_in[0];
  const int* labels = (const int*)d_in[1];
  float* out        = (float*)d_out;

  unsigned short* FB = (unsigned short*)d_ws;                       // 8 MB bf16
  float* S = (float*)((char*)d_ws + (size_t)NROW * DIM * 2);        // 64 MB f32

  hipMemsetAsync(out, 0, sizeof(float), stream);
  normalize_k<<<NROW, 256, 0, stream>>>(X, FB);
  gemm_sim<<<1024, 256, 0, stream>>>(FB, S);
  row_loss_k<<<NROW / 4, 256, 0, stream>>>(S, labels, out);
}